// Round 6
// baseline (294.826 us; speedup 1.0000x reference)
//
#include <hip/hip_runtime.h>
#include <hip/hip_bf16.h>
#include <math.h>

// Problem constants (B=4, T=2048, C=1024, H=16, HS=64)
#define BB 4
#define TT 2048
#define CC 1024
#define HH 16
#define HS 64
#define ROWS (BB*TT)          // 8192

typedef __bf16 bf16_t;
typedef __bf16 bf16x8 __attribute__((ext_vector_type(8)));
typedef __bf16 bf16x4v __attribute__((ext_vector_type(4)));
typedef float  f32x4  __attribute__((ext_vector_type(4)));

// async global->LDS, 16B per lane; LDS dest is wave-uniform base + lane*16
#define GLDS16(g, l) __builtin_amdgcn_global_load_lds( \
    (const __attribute__((address_space(1))) void*)(g), \
    (__attribute__((address_space(3))) void*)(l), 16, 0, 0)

// ---------------------------------------------------------------------------
// fp32 -> bf16 convert (linear)
// ---------------------------------------------------------------------------
__global__ __launch_bounds__(256) void conv_x_kernel(
    const float* __restrict__ x, bf16_t* __restrict__ xbf)
{
    const size_t i = ((size_t)blockIdx.x * 256 + threadIdx.x) * 8;
    const float4 a = *reinterpret_cast<const float4*>(&x[i]);
    const float4 b = *reinterpret_cast<const float4*>(&x[i + 4]);
    bf16x8 o;
    o[0] = (bf16_t)a.x; o[1] = (bf16_t)a.y; o[2] = (bf16_t)a.z; o[3] = (bf16_t)a.w;
    o[4] = (bf16_t)b.x; o[5] = (bf16_t)b.y; o[6] = (bf16_t)b.z; o[7] = (bf16_t)b.w;
    *reinterpret_cast<bf16x8*>(&xbf[i]) = o;
}

// ---------------------------------------------------------------------------
// Weight transpose + convert:  Wt[n][k] = (bf16) W[k][n]     (1024x1024)
// ---------------------------------------------------------------------------
__global__ __launch_bounds__(256) void conv_wt_kernel(
    const float* __restrict__ W, bf16_t* __restrict__ Wt)
{
    __shared__ float t[64][65];
    const int tid = threadIdx.x;
    const int r0 = blockIdx.y * 64, c0 = blockIdx.x * 64;
    #pragma unroll
    for (int l = 0; l < 16; ++l) {
        int idx = tid + l * 256;            // 0..4095
        int rr = idx >> 6, cc = idx & 63;
        t[rr][cc] = W[(size_t)(r0 + rr) * CC + c0 + cc];
    }
    __syncthreads();
    #pragma unroll
    for (int l = 0; l < 16; ++l) {
        int idx = tid + l * 256;
        int rr = idx >> 6, cc = idx & 63;
        Wt[(size_t)(c0 + rr) * CC + r0 + cc] = (bf16_t)t[cc][rr];
    }
}

// ---------------------------------------------------------------------------
// W1/W2 (64x64 fp32) -> transposed bf16:  WT[n][k] = (bf16) W[k][n]
// ---------------------------------------------------------------------------
__global__ __launch_bounds__(256) void conv_w64_kernel(
    const float* __restrict__ W1, const float* __restrict__ W2,
    bf16_t* __restrict__ W1T, bf16_t* __restrict__ W2T)
{
    __shared__ float t1[64][65], t2[64][65];
    const int tid = threadIdx.x;
    #pragma unroll
    for (int l = 0; l < 16; ++l) {
        int idx = tid + l * 256;
        int rr = idx >> 6, cc = idx & 63;
        t1[rr][cc] = W1[idx]; t2[rr][cc] = W2[idx];
    }
    __syncthreads();
    #pragma unroll
    for (int l = 0; l < 16; ++l) {
        int idx = tid + l * 256;
        int rr = idx >> 6, cc = idx & 63;
        W1T[idx] = (bf16_t)t1[cc][rr];
        W2T[idx] = (bf16_t)t2[cc][rr];
    }
}

// ---------------------------------------------------------------------------
// MFMA GEMM (m97 structure): C[M,1024] = A[M,1024] @ W + bias
//   MODE 0: fp32 linear out.  MODE 1: bf16 linear out.
// ---------------------------------------------------------------------------
template<int MODE>
__global__ __launch_bounds__(256) void mfma_gemm_kernel(
    const bf16_t* __restrict__ A, const bf16_t* __restrict__ Bt,
    const float* __restrict__ bias, void* __restrict__ Cout)
{
    __shared__ uint32_t smem[(16384 + 16384) / 4];
    char* const sA = (char*)smem;            // [128 m][64 k] bf16, swizzled
    char* const sB = (char*)smem + 16384;    // [128 n][64 k] bf16, swizzled
    const int tid = threadIdx.x;
    const int wave = tid >> 6, lane = tid & 63;
    const int row0 = blockIdx.y * 128, col0 = blockIdx.x * 128;
    const int wr = wave >> 1, wc = wave & 1;
    const int lr = lane & 15, ko = lane >> 4;
    const int xorv = (lr & 7) << 4;                      // read-side swizzle
    const int koff = ((lane & 7) ^ (lane >> 3)) << 3;    // staging inverse swz
    const int mloc8 = lane >> 3;                         // staging row-in-8

    f32x4 acc[4][4];
    #pragma unroll
    for (int i = 0; i < 4; ++i)
        #pragma unroll
        for (int j = 0; j < 4; ++j) acc[i][j] = (f32x4){0.f, 0.f, 0.f, 0.f};

    for (int k0 = 0; k0 < 1024; k0 += 64) {
        if (k0) __syncthreads();
        #pragma unroll
        for (int a = 0; a < 4; ++a) {
            const int m = wave * 32 + a * 8 + mloc8;     // 0..127, each once
            GLDS16(A  + (size_t)(row0 + m) * CC + k0 + koff,
                   sA + (wave * 4 + a) * 1024);
            GLDS16(Bt + (size_t)(col0 + m) * CC + k0 + koff,
                   sB + (wave * 4 + a) * 1024);
        }
        asm volatile("s_waitcnt vmcnt(0)" ::: "memory");
        __syncthreads();
        #pragma unroll
        for (int ks = 0; ks < 2; ++ks) {
            bf16x8 af[4], bfr[4];
            const int kb = (ks * 64 + ko * 16) ^ xorv;
            #pragma unroll
            for (int mi = 0; mi < 4; ++mi)
                af[mi] = *reinterpret_cast<const bf16x8*>(
                    sA + (wr * 64 + mi * 16 + lr) * 128 + kb);
            #pragma unroll
            for (int ni = 0; ni < 4; ++ni)
                bfr[ni] = *reinterpret_cast<const bf16x8*>(
                    sB + (wc * 64 + ni * 16 + lr) * 128 + kb);
            #pragma unroll
            for (int mi = 0; mi < 4; ++mi)
                #pragma unroll
                for (int ni = 0; ni < 4; ++ni)
                    acc[mi][ni] = __builtin_amdgcn_mfma_f32_16x16x32_bf16(
                        af[mi], bfr[ni], acc[mi][ni], 0, 0, 0);
        }
    }

    float bv[4];
    #pragma unroll
    for (int ni = 0; ni < 4; ++ni) bv[ni] = bias[col0 + wc * 64 + ni * 16 + lr];
    #pragma unroll
    for (int mi = 0; mi < 4; ++mi)
        #pragma unroll
        for (int j = 0; j < 4; ++j) {
            const int grow = row0 + wr * 64 + mi * 16 + ko * 4 + j;
            #pragma unroll
            for (int ni = 0; ni < 4; ++ni) {
                const int gcol = col0 + wc * 64 + ni * 16 + lr;
                const float val = acc[mi][ni][j] + bv[ni];
                if (MODE == 0)
                    ((float*)Cout)[(size_t)grow * CC + gcol] = val;
                else
                    ((bf16_t*)Cout)[(size_t)grow * CC + gcol] = (bf16_t)val;
            }
        }
}

// ---------------------------------------------------------------------------
// MFMA gated transform, transposed output -> vbT [B*H][64][TT]
// ---------------------------------------------------------------------------
__global__ __launch_bounds__(256) void gate_mfma_kernel(
    const bf16_t* __restrict__ vp,      // [ROWS][CC] bf16
    const bf16_t* __restrict__ W1T, const bf16_t* __restrict__ W2T,
    const float* __restrict__ b1, const float* __restrict__ b2,
    bf16_t* __restrict__ vbT)           // [B*H][64][TT]
{
    __shared__ __align__(16) bf16_t Vs[64][64];   // XOR-swizzled rows
    const int tid = threadIdx.x, wave = tid >> 6, lane = tid & 63;
    const int t0 = blockIdx.x * 64;               // global row tile
    const int h = blockIdx.y;
    const int lr = lane & 15, ko = lane >> 4;
    const int koff = ((lane & 7) ^ (lane >> 3)) << 3;
    const int rsub = lane >> 3;

    #pragma unroll
    for (int i = 0; i < 2; ++i) {
        const int rb = (wave * 2 + i) * 8;
        GLDS16(vp + (size_t)(t0 + rb + rsub) * CC + h * 64 + koff,
               (char*)&Vs[rb][0]);
    }
    asm volatile("s_waitcnt vmcnt(0)" ::: "memory");
    __syncthreads();

    bf16x8 w1f[4][2], w2f[4][2];
    #pragma unroll
    for (int ni = 0; ni < 4; ++ni)
        #pragma unroll
        for (int kc = 0; kc < 2; ++kc) {
            w1f[ni][kc] = *reinterpret_cast<const bf16x8*>(
                &W1T[(ni * 16 + lr) * 64 + kc * 32 + ko * 8]);
            w2f[ni][kc] = *reinterpret_cast<const bf16x8*>(
                &W2T[(ni * 16 + lr) * 64 + kc * 32 + ko * 8]);
        }
    const int trow = wave * 16 + lr;
    bf16x8 vf[2];
    #pragma unroll
    for (int kc = 0; kc < 2; ++kc)
        vf[kc] = *reinterpret_cast<const bf16x8*>(
            (char*)Vs + trow * 128 + ((((kc << 2) + ko) ^ (trow & 7)) << 4));

    f32x4 Aacc[4], Gacc[4];
    #pragma unroll
    for (int ni = 0; ni < 4; ++ni) {
        Aacc[ni] = (f32x4){0.f, 0.f, 0.f, 0.f};
        Gacc[ni] = (f32x4){0.f, 0.f, 0.f, 0.f};
    }
    #pragma unroll
    for (int ni = 0; ni < 4; ++ni)
        #pragma unroll
        for (int kc = 0; kc < 2; ++kc) {
            Aacc[ni] = __builtin_amdgcn_mfma_f32_16x16x32_bf16(
                w1f[ni][kc], vf[kc], Aacc[ni], 0, 0, 0);
            Gacc[ni] = __builtin_amdgcn_mfma_f32_16x16x32_bf16(
                w2f[ni][kc], vf[kc], Gacc[ni], 0, 0, 0);
        }

    const int bidx = t0 >> 11;
    const int tb = (t0 & 2047) + trow;
    const size_t obase = (size_t)(bidx * HH + h) * HS * TT;
    #pragma unroll
    for (int ni = 0; ni < 4; ++ni)
        #pragma unroll
        for (int j = 0; j < 4; ++j) {
            const int d = ni * 16 + ko * 4 + j;
            const float vterm = (float)*(const bf16_t*)(
                (const char*)Vs + trow * 128 +
                ((((d >> 3) ^ (trow & 7)) << 4) + (d & 7) * 2));
            const float a = Aacc[ni][j] + b1[d];
            const float g = Gacc[ni][j] + b2[d];
            const float val = (vterm + a) * (1.f / (1.f + __expf(-g)));
            vbT[obase + (size_t)d * TT + tb] = (bf16_t)val;
        }
}

// ---------------------------------------------------------------------------
// MFMA flash attention v5: 8 waves (512 thr) x 32 q = 256 q-rows per block.
// Swapped QK^T softmax (raw-S units, scale folded into exp2 arg), defer-max,
// setprio around MFMA clusters, KV LDS double-buffer shared by 8 waves.
// ---------------------------------------------------------------------------
#define KSCALE 0.04508422002778011f   /* (1/32) * log2(e) */
#define RTHR   256.0f                 /* defer-max threshold in raw-S units */

__global__ __launch_bounds__(512) void attn_mfma5_kernel(
    const bf16_t* __restrict__ ubf, const bf16_t* __restrict__ xbf,
    const bf16_t* __restrict__ vbT, bf16_t* __restrict__ ybf)
{
    __shared__ __align__(16) bf16_t KV[2][2][64][64];   // [buf][K|VT][row][64]
    __shared__ __align__(16) bf16_t Pl[8][32][64];      // per-wave P^T[q][k]

    const int tid = threadIdx.x, wave = tid >> 6, lane = tid & 63;
    const int qg = (int)(gridDim.x - 1 - blockIdx.x);   // heavy groups first
    const int h = blockIdx.y, b = blockIdx.z;
    const int q0 = qg * 256 + wave * 32;
    const size_t rbase = (size_t)b * TT;
    const int hcol = h * 64;
    const size_t hVT = (size_t)(b * HH + h) * HS * TT;
    const int lr = lane & 15, ko = lane >> 4;
    const int koff = ((lane & 7) ^ (lane >> 3)) << 3;
    const int rsub = lane >> 3;
    char* const Pb = (char*)&Pl[wave][0][0];

    // Q fragments (B-operand of swapped QK): lane lr = query row
    bf16x8 qf[2][2];
    #pragma unroll
    for (int mi = 0; mi < 2; ++mi)
        #pragma unroll
        for (int c = 0; c < 2; ++c)
            qf[mi][c] = *reinterpret_cast<const bf16x8*>(
                &ubf[(rbase + q0 + mi * 16 + lr) * CC + hcol + c * 32 + ko * 8]);

    f32x4 O[2][4];                     // O^T: col=lane&15=q, row=ko*4+j=d
    float m_[2], l_[2];
    #pragma unroll
    for (int mi = 0; mi < 2; ++mi) {
        #pragma unroll
        for (int dt = 0; dt < 4; ++dt) O[mi][dt] = (f32x4){0.f, 0.f, 0.f, 0.f};
        m_[mi] = -1e30f; l_[mi] = 0.f;
    }

    const int myntiles = (q0 + 95) >> 6;       // ceil((q0+32)/64)
    const int maxtiles = 4 * qg + 4;

    // ---- stage tile 0 (wave stages K rows [wave*8, +8) and VT rows same)
    {
        const int rb = wave * 8;
        GLDS16(xbf + (rbase + rb + rsub) * CC + hcol + koff, (char*)&KV[0][0][rb][0]);
        GLDS16(vbT + hVT + (size_t)(rb + rsub) * TT + koff,  (char*)&KV[0][1][rb][0]);
    }
    asm volatile("s_waitcnt vmcnt(0)" ::: "memory");
    __syncthreads();

    int buf = 0;
    for (int kt = 0; kt < maxtiles; ++kt) {
        const int k0 = kt * 64;
        if (kt + 1 < maxtiles) {
            const int kn = k0 + 64;
            const int rb = wave * 8;
            GLDS16(xbf + (rbase + kn + rb + rsub) * CC + hcol + koff,
                   (char*)&KV[buf ^ 1][0][rb][0]);
            GLDS16(vbT + hVT + (size_t)(rb + rsub) * TT + kn + koff,
                   (char*)&KV[buf ^ 1][1][rb][0]);
        }

        if (kt < myntiles) {
            char* const Kb = (char*)&KV[buf][0][0][0];
            char* const Vb = (char*)&KV[buf][1][0][0];
            bf16x8 kf[4][2];
            #pragma unroll
            for (int nt = 0; nt < 4; ++nt)
                #pragma unroll
                for (int c = 0; c < 2; ++c)
                    kf[nt][c] = *reinterpret_cast<const bf16x8*>(
                        Kb + (nt * 16 + lr) * 128 + ((((c << 2) + ko) ^ (lr & 7)) << 4));
            // S^T = K @ U^T (raw units): col=query, row=key
            f32x4 S[2][4];
            __builtin_amdgcn_s_setprio(1);
            #pragma unroll
            for (int mi = 0; mi < 2; ++mi)
                #pragma unroll
                for (int nt = 0; nt < 4; ++nt) {
                    f32x4 s = (f32x4){0.f, 0.f, 0.f, 0.f};
                    s = __builtin_amdgcn_mfma_f32_16x16x32_bf16(kf[nt][0], qf[mi][0], s, 0, 0, 0);
                    s = __builtin_amdgcn_mfma_f32_16x16x32_bf16(kf[nt][1], qf[mi][1], s, 0, 0, 0);
                    S[mi][nt] = s;
                }
            __builtin_amdgcn_s_setprio(0);

            const bool diag = (kt == myntiles - 1);
            #pragma unroll
            for (int mi = 0; mi < 2; ++mi) {
                const int qr = q0 + mi * 16 + lr;
                float mx = -1e30f;
                #pragma unroll
                for (int nt = 0; nt < 4; ++nt)
                    #pragma unroll
                    for (int j = 0; j < 4; ++j) {
                        float val = S[mi][nt][j];
                        if (diag && (k0 + nt * 16 + ko * 4 + j) > qr) val = -1e30f;
                        S[mi][nt][j] = val;
                        mx = fmaxf(mx, val);
                    }
                mx = fmaxf(mx, __shfl_xor(mx, 16));
                mx = fmaxf(mx, __shfl_xor(mx, 32));
                // defer-max: only rescale when the max moved materially
                if (!__all(mx - m_[mi] <= RTHR)) {
                    const float mnew = fmaxf(m_[mi], mx);
                    const float sc = exp2f((m_[mi] - mnew) * KSCALE);
                    m_[mi] = mnew;
                    l_[mi] *= sc;
                    #pragma unroll
                    for (int dt = 0; dt < 4; ++dt)
                        #pragma unroll
                        for (int j = 0; j < 4; ++j) O[mi][dt][j] *= sc;
                }
                const float mcur = m_[mi];
                float psum = 0.f;
                #pragma unroll
                for (int nt = 0; nt < 4; ++nt) {
                    bf16x4v pw;
                    #pragma unroll
                    for (int j = 0; j < 4; ++j) {
                        float p = exp2f((S[mi][nt][j] - mcur) * KSCALE);
                        psum += p;
                        pw[j] = (bf16_t)p;
                    }
                    *reinterpret_cast<bf16x4v*>(
                        Pb + (mi * 16 + lr) * 128 +
                        ((((nt << 1) + (ko >> 1)) ^ (lr & 7)) << 4) + ((ko & 1) << 3)) = pw;
                }
                psum += __shfl_xor(psum, 16);
                psum += __shfl_xor(psum, 32);
                l_[mi] += psum;
            }

            // O^T += V^T @ P^T
            bf16x8 vt[4][2], pf[2][2];
            #pragma unroll
            for (int dt = 0; dt < 4; ++dt)
                #pragma unroll
                for (int c = 0; c < 2; ++c)
                    vt[dt][c] = *reinterpret_cast<const bf16x8*>(
                        Vb + (dt * 16 + lr) * 128 + ((((c << 2) + ko) ^ (lr & 7)) << 4));
            #pragma unroll
            for (int mi = 0; mi < 2; ++mi)
                #pragma unroll
                for (int ks = 0; ks < 2; ++ks)
                    pf[mi][ks] = *reinterpret_cast<const bf16x8*>(
                        Pb + (mi * 16 + lr) * 128 + ((((ks << 2) + ko) ^ (lr & 7)) << 4));
            __builtin_amdgcn_s_setprio(1);
            #pragma unroll
            for (int mi = 0; mi < 2; ++mi)
                #pragma unroll
                for (int dt = 0; dt < 4; ++dt) {
                    O[mi][dt] = __builtin_amdgcn_mfma_f32_16x16x32_bf16(
                        vt[dt][0], pf[mi][0], O[mi][dt], 0, 0, 0);
                    O[mi][dt] = __builtin_amdgcn_mfma_f32_16x16x32_bf16(
                        vt[dt][1], pf[mi][1], O[mi][dt], 0, 0, 0);
                }
            __builtin_amdgcn_s_setprio(0);
        }

        asm volatile("s_waitcnt vmcnt(0)" ::: "memory");
        __syncthreads();
        buf ^= 1;
    }

    // epilogue: lane holds query q0+mi*16+lr, d = dt*16+ko*4+j
    #pragma unroll
    for (int mi = 0; mi < 2; ++mi) {
        const float inv = 1.f / l_[mi];
        const size_t grow = rbase + q0 + mi * 16 + lr;
        #pragma unroll
        for (int dt = 0; dt < 4; ++dt) {
            bf16x4v o4;
            #pragma unroll
            for (int j = 0; j < 4; ++j) o4[j] = (bf16_t)(O[mi][dt][j] * inv);
            *reinterpret_cast<bf16x4v*>(
                &ybf[grow * CC + hcol + dt * 16 + ko * 4]) = o4;
        }
    }
}

// ---------------------------------------------------------------------------
extern "C" void kernel_launch(void* const* d_in, const int* in_sizes, int n_in,
                              void* d_out, int out_size, void* d_ws, size_t ws_size,
                              hipStream_t stream)
{
    (void)in_sizes; (void)n_in; (void)out_size; (void)ws_size;
    const float* x  = (const float*)d_in[0];
    const float* Wu = (const float*)d_in[1];
    const float* bu = (const float*)d_in[2];
    const float* Wv = (const float*)d_in[3];
    const float* bv = (const float*)d_in[4];
    const float* W1 = (const float*)d_in[5];
    const float* b1 = (const float*)d_in[6];
    const float* W2 = (const float*)d_in[7];
    const float* b2 = (const float*)d_in[8];
    const float* Wp = (const float*)d_in[9];
    const float* bp = (const float*)d_in[10];
    float* out = (float*)d_out;

    const size_t NE = (size_t)ROWS * CC;
    bf16_t* xbf = (bf16_t*)d_ws;                    // 16 MB
    bf16_t* ubf = xbf + NE;                         // 16 MB
    bf16_t* vp  = ubf + NE;                         // 16 MB
    bf16_t* vbT = vp  + NE;                         // 16 MB
    bf16_t* WuT = vbT + NE;                         // 2 MB
    bf16_t* WvT = WuT + (size_t)CC * CC;            // 2 MB
    bf16_t* WpT = WvT + (size_t)CC * CC;            // 2 MB
    bf16_t* W1T = WpT + (size_t)CC * CC;            // 8 KB
    bf16_t* W2T = W1T + (size_t)HS * HS;            // 8 KB
    bf16_t* ybf = vp;                               // alias: vp dead after gate

    conv_x_kernel<<<ROWS * CC / (256 * 8), 256, 0, stream>>>(x, xbf);
    conv_wt_kernel<<<dim3(16, 16), 256, 0, stream>>>(Wu, WuT);
    conv_wt_kernel<<<dim3(16, 16), 256, 0, stream>>>(Wv, WvT);
    conv_wt_kernel<<<dim3(16, 16), 256, 0, stream>>>(Wp, WpT);
    conv_w64_kernel<<<1, 256, 0, stream>>>(W1, W2, W1T, W2T);

    dim3 gemm_grid(CC / 128, ROWS / 128);           // (8, 64)
    mfma_gemm_kernel<1><<<gemm_grid, 256, 0, stream>>>(xbf, WuT, bu, ubf);
    mfma_gemm_kernel<1><<<gemm_grid, 256, 0, stream>>>(xbf, WvT, bv, vp);
    gate_mfma_kernel<<<dim3(ROWS / 64, HH), 256, 0, stream>>>(
        vp, W1T, W2T, b1, b2, vbT);
    attn_mfma5_kernel<<<dim3(TT / 256, HH, BB), 512, 0, stream>>>(
        ubf, xbf, vbT, ybf);
    mfma_gemm_kernel<0><<<gemm_grid, 256, 0, stream>>>(ybf, WpT, bp, out);
}

// Round 7
// 247.513 us; speedup vs baseline: 1.1912x; 1.1912x over previous
//
#include <hip/hip_runtime.h>
#include <hip/hip_bf16.h>
#include <math.h>

// Problem constants (B=4, T=2048, C=1024, H=16, HS=64)
#define BB 4
#define TT 2048
#define CC 1024
#define HH 16
#define HS 64
#define ROWS (BB*TT)          // 8192

typedef __bf16 bf16_t;
typedef __bf16 bf16x8 __attribute__((ext_vector_type(8)));
typedef __bf16 bf16x4v __attribute__((ext_vector_type(4)));
typedef float  f32x4  __attribute__((ext_vector_type(4)));

// async global->LDS, 16B per lane; LDS dest is wave-uniform base + lane*16
#define GLDS16(g, l) __builtin_amdgcn_global_load_lds( \
    (const __attribute__((address_space(1))) void*)(g), \
    (__attribute__((address_space(3))) void*)(l), 16, 0, 0)

// ---------------------------------------------------------------------------
// fp32 -> bf16 convert (linear)
// ---------------------------------------------------------------------------
__global__ __launch_bounds__(256) void conv_x_kernel(
    const float* __restrict__ x, bf16_t* __restrict__ xbf)
{
    const size_t i = ((size_t)blockIdx.x * 256 + threadIdx.x) * 8;
    const float4 a = *reinterpret_cast<const float4*>(&x[i]);
    const float4 b = *reinterpret_cast<const float4*>(&x[i + 4]);
    bf16x8 o;
    o[0] = (bf16_t)a.x; o[1] = (bf16_t)a.y; o[2] = (bf16_t)a.z; o[3] = (bf16_t)a.w;
    o[4] = (bf16_t)b.x; o[5] = (bf16_t)b.y; o[6] = (bf16_t)b.z; o[7] = (bf16_t)b.w;
    *reinterpret_cast<bf16x8*>(&xbf[i]) = o;
}

// ---------------------------------------------------------------------------
// Weight transpose + convert:  Wt[n][k] = (bf16) W[k][n]     (1024x1024)
// ---------------------------------------------------------------------------
__global__ __launch_bounds__(256) void conv_wt_kernel(
    const float* __restrict__ W, bf16_t* __restrict__ Wt)
{
    __shared__ float t[64][65];
    const int tid = threadIdx.x;
    const int r0 = blockIdx.y * 64, c0 = blockIdx.x * 64;
    #pragma unroll
    for (int l = 0; l < 16; ++l) {
        int idx = tid + l * 256;            // 0..4095
        int rr = idx >> 6, cc = idx & 63;
        t[rr][cc] = W[(size_t)(r0 + rr) * CC + c0 + cc];
    }
    __syncthreads();
    #pragma unroll
    for (int l = 0; l < 16; ++l) {
        int idx = tid + l * 256;
        int rr = idx >> 6, cc = idx & 63;
        Wt[(size_t)(c0 + rr) * CC + r0 + cc] = (bf16_t)t[cc][rr];
    }
}

// ---------------------------------------------------------------------------
// W1/W2 (64x64 fp32) -> transposed bf16:  WT[n][k] = (bf16) W[k][n]
// ---------------------------------------------------------------------------
__global__ __launch_bounds__(256) void conv_w64_kernel(
    const float* __restrict__ W1, const float* __restrict__ W2,
    bf16_t* __restrict__ W1T, bf16_t* __restrict__ W2T)
{
    __shared__ float t1[64][65], t2[64][65];
    const int tid = threadIdx.x;
    #pragma unroll
    for (int l = 0; l < 16; ++l) {
        int idx = tid + l * 256;
        int rr = idx >> 6, cc = idx & 63;
        t1[rr][cc] = W1[idx]; t2[rr][cc] = W2[idx];
    }
    __syncthreads();
    #pragma unroll
    for (int l = 0; l < 16; ++l) {
        int idx = tid + l * 256;
        int rr = idx >> 6, cc = idx & 63;
        W1T[idx] = (bf16_t)t1[cc][rr];
        W2T[idx] = (bf16_t)t2[cc][rr];
    }
}

// ---------------------------------------------------------------------------
// MFMA GEMM (m97 structure): C[M,1024] = A[M,1024] @ W + bias
//   MODE 0: fp32 linear out.  MODE 1: bf16 linear out.
// ---------------------------------------------------------------------------
template<int MODE>
__global__ __launch_bounds__(256) void mfma_gemm_kernel(
    const bf16_t* __restrict__ A, const bf16_t* __restrict__ Bt,
    const float* __restrict__ bias, void* __restrict__ Cout)
{
    __shared__ uint32_t smem[(16384 + 16384) / 4];
    char* const sA = (char*)smem;            // [128 m][64 k] bf16, swizzled
    char* const sB = (char*)smem + 16384;    // [128 n][64 k] bf16, swizzled
    const int tid = threadIdx.x;
    const int wave = tid >> 6, lane = tid & 63;
    const int row0 = blockIdx.y * 128, col0 = blockIdx.x * 128;
    const int wr = wave >> 1, wc = wave & 1;
    const int lr = lane & 15, ko = lane >> 4;
    const int xorv = (lr & 7) << 4;                      // read-side swizzle
    const int koff = ((lane & 7) ^ (lane >> 3)) << 3;    // staging inverse swz
    const int mloc8 = lane >> 3;                         // staging row-in-8

    f32x4 acc[4][4];
    #pragma unroll
    for (int i = 0; i < 4; ++i)
        #pragma unroll
        for (int j = 0; j < 4; ++j) acc[i][j] = (f32x4){0.f, 0.f, 0.f, 0.f};

    for (int k0 = 0; k0 < 1024; k0 += 64) {
        if (k0) __syncthreads();
        #pragma unroll
        for (int a = 0; a < 4; ++a) {
            const int m = wave * 32 + a * 8 + mloc8;     // 0..127, each once
            GLDS16(A  + (size_t)(row0 + m) * CC + k0 + koff,
                   sA + (wave * 4 + a) * 1024);
            GLDS16(Bt + (size_t)(col0 + m) * CC + k0 + koff,
                   sB + (wave * 4 + a) * 1024);
        }
        asm volatile("s_waitcnt vmcnt(0)" ::: "memory");
        __syncthreads();
        #pragma unroll
        for (int ks = 0; ks < 2; ++ks) {
            bf16x8 af[4], bfr[4];
            const int kb = (ks * 64 + ko * 16) ^ xorv;
            #pragma unroll
            for (int mi = 0; mi < 4; ++mi)
                af[mi] = *reinterpret_cast<const bf16x8*>(
                    sA + (wr * 64 + mi * 16 + lr) * 128 + kb);
            #pragma unroll
            for (int ni = 0; ni < 4; ++ni)
                bfr[ni] = *reinterpret_cast<const bf16x8*>(
                    sB + (wc * 64 + ni * 16 + lr) * 128 + kb);
            #pragma unroll
            for (int mi = 0; mi < 4; ++mi)
                #pragma unroll
                for (int ni = 0; ni < 4; ++ni)
                    acc[mi][ni] = __builtin_amdgcn_mfma_f32_16x16x32_bf16(
                        af[mi], bfr[ni], acc[mi][ni], 0, 0, 0);
        }
    }

    float bv[4];
    #pragma unroll
    for (int ni = 0; ni < 4; ++ni) bv[ni] = bias[col0 + wc * 64 + ni * 16 + lr];
    #pragma unroll
    for (int mi = 0; mi < 4; ++mi)
        #pragma unroll
        for (int j = 0; j < 4; ++j) {
            const int grow = row0 + wr * 64 + mi * 16 + ko * 4 + j;
            #pragma unroll
            for (int ni = 0; ni < 4; ++ni) {
                const int gcol = col0 + wc * 64 + ni * 16 + lr;
                const float val = acc[mi][ni][j] + bv[ni];
                if (MODE == 0)
                    ((float*)Cout)[(size_t)grow * CC + gcol] = val;
                else
                    ((bf16_t*)Cout)[(size_t)grow * CC + gcol] = (bf16_t)val;
            }
        }
}

// ---------------------------------------------------------------------------
// MFMA gated transform, transposed output -> vbT [B*H][64][TT]
// ---------------------------------------------------------------------------
__global__ __launch_bounds__(256) void gate_mfma_kernel(
    const bf16_t* __restrict__ vp,      // [ROWS][CC] bf16
    const bf16_t* __restrict__ W1T, const bf16_t* __restrict__ W2T,
    const float* __restrict__ b1, const float* __restrict__ b2,
    bf16_t* __restrict__ vbT)           // [B*H][64][TT]
{
    __shared__ __align__(16) bf16_t Vs[64][64];   // XOR-swizzled rows
    const int tid = threadIdx.x, wave = tid >> 6, lane = tid & 63;
    const int t0 = blockIdx.x * 64;               // global row tile
    const int h = blockIdx.y;
    const int lr = lane & 15, ko = lane >> 4;
    const int koff = ((lane & 7) ^ (lane >> 3)) << 3;
    const int rsub = lane >> 3;

    #pragma unroll
    for (int i = 0; i < 2; ++i) {
        const int rb = (wave * 2 + i) * 8;
        GLDS16(vp + (size_t)(t0 + rb + rsub) * CC + h * 64 + koff,
               (char*)&Vs[rb][0]);
    }
    asm volatile("s_waitcnt vmcnt(0)" ::: "memory");
    __syncthreads();

    bf16x8 w1f[4][2], w2f[4][2];
    #pragma unroll
    for (int ni = 0; ni < 4; ++ni)
        #pragma unroll
        for (int kc = 0; kc < 2; ++kc) {
            w1f[ni][kc] = *reinterpret_cast<const bf16x8*>(
                &W1T[(ni * 16 + lr) * 64 + kc * 32 + ko * 8]);
            w2f[ni][kc] = *reinterpret_cast<const bf16x8*>(
                &W2T[(ni * 16 + lr) * 64 + kc * 32 + ko * 8]);
        }
    const int trow = wave * 16 + lr;
    bf16x8 vf[2];
    #pragma unroll
    for (int kc = 0; kc < 2; ++kc)
        vf[kc] = *reinterpret_cast<const bf16x8*>(
            (char*)Vs + trow * 128 + ((((kc << 2) + ko) ^ (trow & 7)) << 4));

    f32x4 Aacc[4], Gacc[4];
    #pragma unroll
    for (int ni = 0; ni < 4; ++ni) {
        Aacc[ni] = (f32x4){0.f, 0.f, 0.f, 0.f};
        Gacc[ni] = (f32x4){0.f, 0.f, 0.f, 0.f};
    }
    #pragma unroll
    for (int ni = 0; ni < 4; ++ni)
        #pragma unroll
        for (int kc = 0; kc < 2; ++kc) {
            Aacc[ni] = __builtin_amdgcn_mfma_f32_16x16x32_bf16(
                w1f[ni][kc], vf[kc], Aacc[ni], 0, 0, 0);
            Gacc[ni] = __builtin_amdgcn_mfma_f32_16x16x32_bf16(
                w2f[ni][kc], vf[kc], Gacc[ni], 0, 0, 0);
        }

    const int bidx = t0 >> 11;
    const int tb = (t0 & 2047) + trow;
    const size_t obase = (size_t)(bidx * HH + h) * HS * TT;
    #pragma unroll
    for (int ni = 0; ni < 4; ++ni)
        #pragma unroll
        for (int j = 0; j < 4; ++j) {
            const int d = ni * 16 + ko * 4 + j;
            const float vterm = (float)*(const bf16_t*)(
                (const char*)Vs + trow * 128 +
                ((((d >> 3) ^ (trow & 7)) << 4) + (d & 7) * 2));
            const float a = Aacc[ni][j] + b1[d];
            const float g = Gacc[ni][j] + b2[d];
            const float val = (vterm + a) * (1.f / (1.f + __expf(-g)));
            vbT[obase + (size_t)d * TT + tb] = (bf16_t)val;
        }
}

// ---------------------------------------------------------------------------
// MFMA flash attention v6: 4 waves x 32 q = 128 q-rows/block (3 blocks/CU);
// qg-mixing block remap for CU load balance; peeled diagonal tile (mask VALU
// only on diag); swapped QK^T softmax in raw-S units (exp2, folded scale);
// defer-max; setprio around MFMA clusters; KV LDS double-buffer.
// ---------------------------------------------------------------------------
#define KSCALE 0.04508422002778011f   /* (1/32) * log2(e) */
#define RTHR   256.0f                 /* defer-max threshold in raw-S units */

__global__ __launch_bounds__(256) void attn_mfma6_kernel(
    const bf16_t* __restrict__ ubf, const bf16_t* __restrict__ xbf,
    const bf16_t* __restrict__ vbT, bf16_t* __restrict__ ybf)
{
    __shared__ __align__(16) bf16_t KV[2][2][64][64];   // [buf][K|VT][row][64]
    __shared__ __align__(16) bf16_t Pl[4][32][64];      // per-wave P^T[q][k]

    const int tid = threadIdx.x, wave = tid >> 6, lane = tid & 63;
    // qg-mixing: co-resident blocks (same x, different z/y) get different qg
    const int qg = (int)((blockIdx.x + blockIdx.y + 4 * blockIdx.z) & 15);
    const int h = blockIdx.y, b = blockIdx.z;
    const int q0 = qg * 128 + wave * 32;
    const size_t rbase = (size_t)b * TT;
    const int hcol = h * 64;
    const size_t hVT = (size_t)(b * HH + h) * HS * TT;
    const int lr = lane & 15, ko = lane >> 4;
    const int koff = ((lane & 7) ^ (lane >> 3)) << 3;
    const int rsub = lane >> 3;
    char* const Pb = (char*)&Pl[wave][0][0];

    // Q fragments (B-operand of swapped QK): lane lr = query row
    bf16x8 qf[2][2];
    #pragma unroll
    for (int mi = 0; mi < 2; ++mi)
        #pragma unroll
        for (int c = 0; c < 2; ++c)
            qf[mi][c] = *reinterpret_cast<const bf16x8*>(
                &ubf[(rbase + q0 + mi * 16 + lr) * CC + hcol + c * 32 + ko * 8]);

    f32x4 O[2][4];                     // O^T: col=lane&15=q, row=ko*4+j=d
    float m_[2], l_[2];
    #pragma unroll
    for (int mi = 0; mi < 2; ++mi) {
        #pragma unroll
        for (int dt = 0; dt < 4; ++dt) O[mi][dt] = (f32x4){0.f, 0.f, 0.f, 0.f};
        m_[mi] = -1e30f; l_[mi] = 0.f;
    }

    const int myntiles = (q0 + 95) >> 6;       // ceil((q0+32)/64)
    const int maxtiles = 2 * qg + 2;

    // ---- stage tile 0
    #pragma unroll
    for (int i = 0; i < 2; ++i) {
        const int rb = (wave * 2 + i) * 8;
        GLDS16(xbf + (rbase + rb + rsub) * CC + hcol + koff, (char*)&KV[0][0][rb][0]);
        GLDS16(vbT + hVT + (size_t)(rb + rsub) * TT + koff,  (char*)&KV[0][1][rb][0]);
    }
    asm volatile("s_waitcnt vmcnt(0)" ::: "memory");
    __syncthreads();

    int buf = 0;
    for (int kt = 0; kt < maxtiles; ++kt) {
        const int k0 = kt * 64;
        if (kt + 1 < maxtiles) {
            const int kn = k0 + 64;
            #pragma unroll
            for (int i = 0; i < 2; ++i) {
                const int rb = (wave * 2 + i) * 8;
                GLDS16(xbf + (rbase + kn + rb + rsub) * CC + hcol + koff,
                       (char*)&KV[buf ^ 1][0][rb][0]);
                GLDS16(vbT + hVT + (size_t)(rb + rsub) * TT + kn + koff,
                       (char*)&KV[buf ^ 1][1][rb][0]);
            }
        }

        if (kt < myntiles) {
            char* const Kb = (char*)&KV[buf][0][0][0];
            char* const Vb = (char*)&KV[buf][1][0][0];
            bf16x8 kf[4][2];
            #pragma unroll
            for (int nt = 0; nt < 4; ++nt)
                #pragma unroll
                for (int c = 0; c < 2; ++c)
                    kf[nt][c] = *reinterpret_cast<const bf16x8*>(
                        Kb + (nt * 16 + lr) * 128 + ((((c << 2) + ko) ^ (lr & 7)) << 4));
            // S^T = K @ U^T (raw units): col=query, row=key
            f32x4 S[2][4];
            __builtin_amdgcn_s_setprio(1);
            #pragma unroll
            for (int mi = 0; mi < 2; ++mi)
                #pragma unroll
                for (int nt = 0; nt < 4; ++nt) {
                    f32x4 s = (f32x4){0.f, 0.f, 0.f, 0.f};
                    s = __builtin_amdgcn_mfma_f32_16x16x32_bf16(kf[nt][0], qf[mi][0], s, 0, 0, 0);
                    s = __builtin_amdgcn_mfma_f32_16x16x32_bf16(kf[nt][1], qf[mi][1], s, 0, 0, 0);
                    S[mi][nt] = s;
                }
            __builtin_amdgcn_s_setprio(0);

            const bool diag = (kt == myntiles - 1);   // wave-uniform
            #pragma unroll
            for (int mi = 0; mi < 2; ++mi) {
                float mx = -1e30f;
                if (diag) {
                    const int qr = q0 + mi * 16 + lr;
                    #pragma unroll
                    for (int nt = 0; nt < 4; ++nt)
                        #pragma unroll
                        for (int j = 0; j < 4; ++j) {
                            float val = S[mi][nt][j];
                            if ((k0 + nt * 16 + ko * 4 + j) > qr) val = -1e30f;
                            S[mi][nt][j] = val;
                            mx = fmaxf(mx, val);
                        }
                } else {
                    #pragma unroll
                    for (int nt = 0; nt < 4; ++nt)
                        #pragma unroll
                        for (int j = 0; j < 4; ++j)
                            mx = fmaxf(mx, S[mi][nt][j]);
                }
                mx = fmaxf(mx, __shfl_xor(mx, 16));
                mx = fmaxf(mx, __shfl_xor(mx, 32));
                // defer-max: only rescale when the max moved materially
                if (!__all(mx - m_[mi] <= RTHR)) {
                    const float mnew = fmaxf(m_[mi], mx);
                    const float sc = exp2f((m_[mi] - mnew) * KSCALE);
                    m_[mi] = mnew;
                    l_[mi] *= sc;
                    #pragma unroll
                    for (int dt = 0; dt < 4; ++dt)
                        #pragma unroll
                        for (int j = 0; j < 4; ++j) O[mi][dt][j] *= sc;
                }
                const float mcur = m_[mi];
                float psum = 0.f;
                #pragma unroll
                for (int nt = 0; nt < 4; ++nt) {
                    bf16x4v pw;
                    #pragma unroll
                    for (int j = 0; j < 4; ++j) {
                        float p = exp2f((S[mi][nt][j] - mcur) * KSCALE);
                        psum += p;
                        pw[j] = (bf16_t)p;
                    }
                    *reinterpret_cast<bf16x4v*>(
                        Pb + (mi * 16 + lr) * 128 +
                        ((((nt << 1) + (ko >> 1)) ^ (lr & 7)) << 4) + ((ko & 1) << 3)) = pw;
                }
                psum += __shfl_xor(psum, 16);
                psum += __shfl_xor(psum, 32);
                l_[mi] += psum;
            }

            // O^T += V^T @ P^T
            bf16x8 vt[4][2], pf[2][2];
            #pragma unroll
            for (int dt = 0; dt < 4; ++dt)
                #pragma unroll
                for (int c = 0; c < 2; ++c)
                    vt[dt][c] = *reinterpret_cast<const bf16x8*>(
                        Vb + (dt * 16 + lr) * 128 + ((((c << 2) + ko) ^ (lr & 7)) << 4));
            #pragma unroll
            for (int mi = 0; mi < 2; ++mi)
                #pragma unroll
                for (int ks = 0; ks < 2; ++ks)
                    pf[mi][ks] = *reinterpret_cast<const bf16x8*>(
                        Pb + (mi * 16 + lr) * 128 + ((((ks << 2) + ko) ^ (lr & 7)) << 4));
            __builtin_amdgcn_s_setprio(1);
            #pragma unroll
            for (int mi = 0; mi < 2; ++mi)
                #pragma unroll
                for (int dt = 0; dt < 4; ++dt) {
                    O[mi][dt] = __builtin_amdgcn_mfma_f32_16x16x32_bf16(
                        vt[dt][0], pf[mi][0], O[mi][dt], 0, 0, 0);
                    O[mi][dt] = __builtin_amdgcn_mfma_f32_16x16x32_bf16(
                        vt[dt][1], pf[mi][1], O[mi][dt], 0, 0, 0);
                }
            __builtin_amdgcn_s_setprio(0);
        }

        asm volatile("s_waitcnt vmcnt(0)" ::: "memory");
        __syncthreads();
        buf ^= 1;
    }

    // epilogue: lane holds query q0+mi*16+lr, d = dt*16+ko*4+j
    #pragma unroll
    for (int mi = 0; mi < 2; ++mi) {
        const float inv = 1.f / l_[mi];
        const size_t grow = rbase + q0 + mi * 16 + lr;
        #pragma unroll
        for (int dt = 0; dt < 4; ++dt) {
            bf16x4v o4;
            #pragma unroll
            for (int j = 0; j < 4; ++j) o4[j] = (bf16_t)(O[mi][dt][j] * inv);
            *reinterpret_cast<bf16x4v*>(
                &ybf[grow * CC + hcol + dt * 16 + ko * 4]) = o4;
        }
    }
}

// ---------------------------------------------------------------------------
extern "C" void kernel_launch(void* const* d_in, const int* in_sizes, int n_in,
                              void* d_out, int out_size, void* d_ws, size_t ws_size,
                              hipStream_t stream)
{
    (void)in_sizes; (void)n_in; (void)out_size; (void)ws_size;
    const float* x  = (const float*)d_in[0];
    const float* Wu = (const float*)d_in[1];
    const float* bu = (const float*)d_in[2];
    const float* Wv = (const float*)d_in[3];
    const float* bv = (const float*)d_in[4];
    const float* W1 = (const float*)d_in[5];
    const float* b1 = (const float*)d_in[6];
    const float* W2 = (const float*)d_in[7];
    const float* b2 = (const float*)d_in[8];
    const float* Wp = (const float*)d_in[9];
    const float* bp = (const float*)d_in[10];
    float* out = (float*)d_out;

    const size_t NE = (size_t)ROWS * CC;
    bf16_t* xbf = (bf16_t*)d_ws;                    // 16 MB
    bf16_t* ubf = xbf + NE;                         // 16 MB
    bf16_t* vp  = ubf + NE;                         // 16 MB
    bf16_t* vbT = vp  + NE;                         // 16 MB
    bf16_t* WuT = vbT + NE;                         // 2 MB
    bf16_t* WvT = WuT + (size_t)CC * CC;            // 2 MB
    bf16_t* WpT = WvT + (size_t)CC * CC;            // 2 MB
    bf16_t* W1T = WpT + (size_t)CC * CC;            // 8 KB
    bf16_t* W2T = W1T + (size_t)HS * HS;            // 8 KB
    bf16_t* ybf = vp;                               // alias: vp dead after gate

    conv_x_kernel<<<ROWS * CC / (256 * 8), 256, 0, stream>>>(x, xbf);
    conv_wt_kernel<<<dim3(16, 16), 256, 0, stream>>>(Wu, WuT);
    conv_wt_kernel<<<dim3(16, 16), 256, 0, stream>>>(Wv, WvT);
    conv_wt_kernel<<<dim3(16, 16), 256, 0, stream>>>(Wp, WpT);
    conv_w64_kernel<<<1, 256, 0, stream>>>(W1, W2, W1T, W2T);

    dim3 gemm_grid(CC / 128, ROWS / 128);           // (8, 64)
    mfma_gemm_kernel<1><<<gemm_grid, 256, 0, stream>>>(xbf, WuT, bu, ubf);
    mfma_gemm_kernel<1><<<gemm_grid, 256, 0, stream>>>(xbf, WvT, bv, vp);
    gate_mfma_kernel<<<dim3(ROWS / 64, HH), 256, 0, stream>>>(
        vp, W1T, W2T, b1, b2, vbT);
    attn_mfma6_kernel<<<dim3(TT / 128, HH, BB), 256, 0, stream>>>(
        ubf, xbf, vbT, ybf);
    mfma_gemm_kernel<0><<<gemm_grid, 256, 0, stream>>>(ybf, WpT, bp, out);
}

// Round 9
// 234.522 us; speedup vs baseline: 1.2571x; 1.0554x over previous
//
#include <hip/hip_runtime.h>
#include <hip/hip_bf16.h>
#include <math.h>

// Problem constants (B=4, T=2048, C=1024, H=16, HS=64)
#define BB 4
#define TT 2048
#define CC 1024
#define HH 16
#define HS 64
#define ROWS (BB*TT)          // 8192

typedef __bf16 bf16_t;
typedef __bf16 bf16x8 __attribute__((ext_vector_type(8)));
typedef __bf16 bf16x4v __attribute__((ext_vector_type(4)));
typedef __bf16 bf16x2 __attribute__((ext_vector_type(2)));
typedef float  f32x4  __attribute__((ext_vector_type(4)));
typedef float  f32x16 __attribute__((ext_vector_type(16)));
typedef unsigned u32x4 __attribute__((ext_vector_type(4)));

// async global->LDS, 16B per lane; LDS dest is wave-uniform base + lane*16
#define GLDS16(g, l) __builtin_amdgcn_global_load_lds( \
    (const __attribute__((address_space(1))) void*)(g), \
    (__attribute__((address_space(3))) void*)(l), 16, 0, 0)

// ---------------------------------------------------------------------------
// fp32 -> bf16 convert (linear)
// ---------------------------------------------------------------------------
__global__ __launch_bounds__(256) void conv_x_kernel(
    const float* __restrict__ x, bf16_t* __restrict__ xbf)
{
    const size_t i = ((size_t)blockIdx.x * 256 + threadIdx.x) * 8;
    const float4 a = *reinterpret_cast<const float4*>(&x[i]);
    const float4 b = *reinterpret_cast<const float4*>(&x[i + 4]);
    bf16x8 o;
    o[0] = (bf16_t)a.x; o[1] = (bf16_t)a.y; o[2] = (bf16_t)a.z; o[3] = (bf16_t)a.w;
    o[4] = (bf16_t)b.x; o[5] = (bf16_t)b.y; o[6] = (bf16_t)b.z; o[7] = (bf16_t)b.w;
    *reinterpret_cast<bf16x8*>(&xbf[i]) = o;
}

// ---------------------------------------------------------------------------
// Weight transpose + convert:  Wt[n][k] = (bf16) W[k][n]     (1024x1024)
// ---------------------------------------------------------------------------
__global__ __launch_bounds__(256) void conv_wt_kernel(
    const float* __restrict__ W, bf16_t* __restrict__ Wt)
{
    __shared__ float t[64][65];
    const int tid = threadIdx.x;
    const int r0 = blockIdx.y * 64, c0 = blockIdx.x * 64;
    #pragma unroll
    for (int l = 0; l < 16; ++l) {
        int idx = tid + l * 256;            // 0..4095
        int rr = idx >> 6, cc = idx & 63;
        t[rr][cc] = W[(size_t)(r0 + rr) * CC + c0 + cc];
    }
    __syncthreads();
    #pragma unroll
    for (int l = 0; l < 16; ++l) {
        int idx = tid + l * 256;
        int rr = idx >> 6, cc = idx & 63;
        Wt[(size_t)(c0 + rr) * CC + r0 + cc] = (bf16_t)t[cc][rr];
    }
}

// ---------------------------------------------------------------------------
// W1/W2 (64x64 fp32) -> transposed bf16:  WT[n][k] = (bf16) W[k][n]
// ---------------------------------------------------------------------------
__global__ __launch_bounds__(256) void conv_w64_kernel(
    const float* __restrict__ W1, const float* __restrict__ W2,
    bf16_t* __restrict__ W1T, bf16_t* __restrict__ W2T)
{
    __shared__ float t1[64][65], t2[64][65];
    const int tid = threadIdx.x;
    #pragma unroll
    for (int l = 0; l < 16; ++l) {
        int idx = tid + l * 256;
        int rr = idx >> 6, cc = idx & 63;
        t1[rr][cc] = W1[idx]; t2[rr][cc] = W2[idx];
    }
    __syncthreads();
    #pragma unroll
    for (int l = 0; l < 16; ++l) {
        int idx = tid + l * 256;
        int rr = idx >> 6, cc = idx & 63;
        W1T[idx] = (bf16_t)t1[cc][rr];
        W2T[idx] = (bf16_t)t2[cc][rr];
    }
}

// ---------------------------------------------------------------------------
// MFMA GEMM (m97 structure): C[M,1024] = A[M,1024] @ W + bias
//   MODE 0: fp32 linear out.  MODE 1: bf16 linear out.
// ---------------------------------------------------------------------------
template<int MODE>
__global__ __launch_bounds__(256) void mfma_gemm_kernel(
    const bf16_t* __restrict__ A, const bf16_t* __restrict__ Bt,
    const float* __restrict__ bias, void* __restrict__ Cout)
{
    __shared__ uint32_t smem[(16384 + 16384) / 4];
    char* const sA = (char*)smem;            // [128 m][64 k] bf16, swizzled
    char* const sB = (char*)smem + 16384;    // [128 n][64 k] bf16, swizzled
    const int tid = threadIdx.x;
    const int wave = tid >> 6, lane = tid & 63;
    const int row0 = blockIdx.y * 128, col0 = blockIdx.x * 128;
    const int wr = wave >> 1, wc = wave & 1;
    const int lr = lane & 15, ko = lane >> 4;
    const int xorv = (lr & 7) << 4;                      // read-side swizzle
    const int koff = ((lane & 7) ^ (lane >> 3)) << 3;    // staging inverse swz
    const int mloc8 = lane >> 3;                         // staging row-in-8

    f32x4 acc[4][4];
    #pragma unroll
    for (int i = 0; i < 4; ++i)
        #pragma unroll
        for (int j = 0; j < 4; ++j) acc[i][j] = (f32x4){0.f, 0.f, 0.f, 0.f};

    for (int k0 = 0; k0 < 1024; k0 += 64) {
        if (k0) __syncthreads();
        #pragma unroll
        for (int a = 0; a < 4; ++a) {
            const int m = wave * 32 + a * 8 + mloc8;     // 0..127, each once
            GLDS16(A  + (size_t)(row0 + m) * CC + k0 + koff,
                   sA + (wave * 4 + a) * 1024);
            GLDS16(Bt + (size_t)(col0 + m) * CC + k0 + koff,
                   sB + (wave * 4 + a) * 1024);
        }
        asm volatile("s_waitcnt vmcnt(0)" ::: "memory");
        __syncthreads();
        #pragma unroll
        for (int ks = 0; ks < 2; ++ks) {
            bf16x8 af[4], bfr[4];
            const int kb = (ks * 64 + ko * 16) ^ xorv;
            #pragma unroll
            for (int mi = 0; mi < 4; ++mi)
                af[mi] = *reinterpret_cast<const bf16x8*>(
                    sA + (wr * 64 + mi * 16 + lr) * 128 + kb);
            #pragma unroll
            for (int ni = 0; ni < 4; ++ni)
                bfr[ni] = *reinterpret_cast<const bf16x8*>(
                    sB + (wc * 64 + ni * 16 + lr) * 128 + kb);
            #pragma unroll
            for (int mi = 0; mi < 4; ++mi)
                #pragma unroll
                for (int ni = 0; ni < 4; ++ni)
                    acc[mi][ni] = __builtin_amdgcn_mfma_f32_16x16x32_bf16(
                        af[mi], bfr[ni], acc[mi][ni], 0, 0, 0);
        }
    }

    float bv[4];
    #pragma unroll
    for (int ni = 0; ni < 4; ++ni) bv[ni] = bias[col0 + wc * 64 + ni * 16 + lr];
    #pragma unroll
    for (int mi = 0; mi < 4; ++mi)
        #pragma unroll
        for (int j = 0; j < 4; ++j) {
            const int grow = row0 + wr * 64 + mi * 16 + ko * 4 + j;
            #pragma unroll
            for (int ni = 0; ni < 4; ++ni) {
                const int gcol = col0 + wc * 64 + ni * 16 + lr;
                const float val = acc[mi][ni][j] + bv[ni];
                if (MODE == 0)
                    ((float*)Cout)[(size_t)grow * CC + gcol] = val;
                else
                    ((bf16_t*)Cout)[(size_t)grow * CC + gcol] = (bf16_t)val;
            }
        }
}

// ---------------------------------------------------------------------------
// MFMA gated transform, transposed output -> vbT [B*H][64][TT].
// Column index within each 16-block is permuted by the involution
// kappa(p) = (p&3) + 8*((p>>2)&1) + 4*(p>>3)   (swaps positions 4-7 <-> 8-11)
// so attention's contiguous V^T fragment reads deliver key slots matching its
// in-register P fragments regardless of the HW 32x32 input k-layout.
// ---------------------------------------------------------------------------
__global__ __launch_bounds__(256) void gate_mfma_kernel(
    const bf16_t* __restrict__ vp,      // [ROWS][CC] bf16
    const bf16_t* __restrict__ W1T, const bf16_t* __restrict__ W2T,
    const float* __restrict__ b1, const float* __restrict__ b2,
    bf16_t* __restrict__ vbT)           // [B*H][64][TT], kappa-permuted cols
{
    __shared__ __align__(16) bf16_t Vs[64][64];   // XOR-swizzled rows
    const int tid = threadIdx.x, wave = tid >> 6, lane = tid & 63;
    const int t0 = blockIdx.x * 64;               // global row tile
    const int h = blockIdx.y;
    const int lr = lane & 15, ko = lane >> 4;
    const int koff = ((lane & 7) ^ (lane >> 3)) << 3;
    const int rsub = lane >> 3;

    #pragma unroll
    for (int i = 0; i < 2; ++i) {
        const int rb = (wave * 2 + i) * 8;
        GLDS16(vp + (size_t)(t0 + rb + rsub) * CC + h * 64 + koff,
               (char*)&Vs[rb][0]);
    }
    asm volatile("s_waitcnt vmcnt(0)" ::: "memory");
    __syncthreads();

    bf16x8 w1f[4][2], w2f[4][2];
    #pragma unroll
    for (int ni = 0; ni < 4; ++ni)
        #pragma unroll
        for (int kc = 0; kc < 2; ++kc) {
            w1f[ni][kc] = *reinterpret_cast<const bf16x8*>(
                &W1T[(ni * 16 + lr) * 64 + kc * 32 + ko * 8]);
            w2f[ni][kc] = *reinterpret_cast<const bf16x8*>(
                &W2T[(ni * 16 + lr) * 64 + kc * 32 + ko * 8]);
        }
    const int trow = wave * 16 + lr;
    bf16x8 vf[2];
    #pragma unroll
    for (int kc = 0; kc < 2; ++kc)
        vf[kc] = *reinterpret_cast<const bf16x8*>(
            (char*)Vs + trow * 128 + ((((kc << 2) + ko) ^ (trow & 7)) << 4));

    f32x4 Aacc[4], Gacc[4];
    #pragma unroll
    for (int ni = 0; ni < 4; ++ni) {
        Aacc[ni] = (f32x4){0.f, 0.f, 0.f, 0.f};
        Gacc[ni] = (f32x4){0.f, 0.f, 0.f, 0.f};
    }
    #pragma unroll
    for (int ni = 0; ni < 4; ++ni)
        #pragma unroll
        for (int kc = 0; kc < 2; ++kc) {
            Aacc[ni] = __builtin_amdgcn_mfma_f32_16x16x32_bf16(
                w1f[ni][kc], vf[kc], Aacc[ni], 0, 0, 0);
            Gacc[ni] = __builtin_amdgcn_mfma_f32_16x16x32_bf16(
                w2f[ni][kc], vf[kc], Gacc[ni], 0, 0, 0);
        }

    const int bidx = t0 >> 11;
    // kappa-permuted output column (involution on lr: 4..7 <-> 8..11)
    const int q2 = (lr >> 2) & 3;
    const int lrk = lr + (q2 == 1 ? 4 : (q2 == 2 ? -4 : 0));
    const int tb = (t0 & 2047) + wave * 16 + lrk;
    const size_t obase = (size_t)(bidx * HH + h) * HS * TT;
    #pragma unroll
    for (int ni = 0; ni < 4; ++ni)
        #pragma unroll
        for (int j = 0; j < 4; ++j) {
            const int d = ni * 16 + ko * 4 + j;
            const float vterm = (float)*(const bf16_t*)(
                (const char*)Vs + trow * 128 +
                ((((d >> 3) ^ (trow & 7)) << 4) + (d & 7) * 2));
            const float a = Aacc[ni][j] + b1[d];
            const float g = Gacc[ni][j] + b2[d];
            const float val = (vterm + a) * (1.f / (1.f + __expf(-g)));
            vbT[obase + (size_t)d * TT + tb] = (bf16_t)val;
        }
}

// ---------------------------------------------------------------------------
// MFMA flash attention v8: 32x32 swapped MFMA; each lane owns ONE query
// (col=lane&31). In-register softmax (1 shfl). P stays LANE-LOCAL: S^T's
// D-regs [8ks..8ks+8) ARE the PV B-fragment for key-chunk ks, paired with
// kappa-staged V^T (see gate) -- correct for any HW input k-layout, no
// cross-lane ops, no LDS for P. 4 waves x 32 q; qg-mixing remap; diag peel;
// defer-max; exp2-clamp; setprio; double-buffered KV staging (32 KB).
// ---------------------------------------------------------------------------
#define KSCALE 0.04508422002778011f   /* (1/32) * log2(e) */
#define RTHR   256.0f                 /* defer-max threshold in raw-S units */

__global__ __launch_bounds__(256) void attn_mfma8_kernel(
    const bf16_t* __restrict__ ubf, const bf16_t* __restrict__ xbf,
    const bf16_t* __restrict__ vbT, bf16_t* __restrict__ ybf)
{
    __shared__ __align__(16) bf16_t KV[2][2][64][64];   // [buf][K|VT][row][64]

    const int tid = threadIdx.x, wave = tid >> 6, lane = tid & 63;
    const int qg = (int)((blockIdx.x + blockIdx.y + 4 * blockIdx.z) & 15);
    const int h = blockIdx.y, b = blockIdx.z;
    const int q0w = qg * 128 + wave * 32;
    const size_t rbase = (size_t)b * TT;
    const int hcol = h * 64;
    const size_t hVT = (size_t)(b * HH + h) * HS * TT;
    const int l31 = lane & 31, hi = lane >> 5;
    const int koff = ((lane & 7) ^ (lane >> 3)) << 3;   // staging inverse swz
    const int rsub = lane >> 3;

    // Q fragments (B-operand): col=query=l31; contiguous 8 per 16-k chunk
    bf16x8 qf[4];
    #pragma unroll
    for (int dk = 0; dk < 4; ++dk)
        qf[dk] = *reinterpret_cast<const bf16x8*>(
            &ubf[(rbase + q0w + l31) * CC + hcol + dk * 16 + hi * 8]);

    f32x16 O[2];
    #pragma unroll
    for (int dt = 0; dt < 2; ++dt)
        #pragma unroll
        for (int r = 0; r < 16; ++r) O[dt][r] = 0.f;
    float m_ = -1e30f, l_ = 0.f;

    const int myntiles = (q0w + 95) >> 6;      // ceil((q0w+32)/64)
    const int maxtiles = 2 * qg + 2;

    // ---- stage tile 0: wave stages K rows [wave*16,+16) and VT rows same
    #pragma unroll
    for (int i = 0; i < 2; ++i) {
        const int rb = wave * 16 + i * 8;
        GLDS16(xbf + (rbase + rb + rsub) * CC + hcol + koff, (char*)&KV[0][0][rb][0]);
        GLDS16(vbT + hVT + (size_t)(rb + rsub) * TT + koff,  (char*)&KV[0][1][rb][0]);
    }
    asm volatile("s_waitcnt vmcnt(0)" ::: "memory");
    __syncthreads();

    int buf = 0;
    for (int kt = 0; kt < maxtiles; ++kt) {
        const int k0 = kt * 64;
        if (kt + 1 < maxtiles) {
            const int kn = k0 + 64;
            #pragma unroll
            for (int i = 0; i < 2; ++i) {
                const int rb = wave * 16 + i * 8;
                GLDS16(xbf + (rbase + kn + rb + rsub) * CC + hcol + koff,
                       (char*)&KV[buf ^ 1][0][rb][0]);
                GLDS16(vbT + hVT + (size_t)(rb + rsub) * TT + kn + koff,
                       (char*)&KV[buf ^ 1][1][rb][0]);
            }
        }

        if (kt < myntiles) {
            const char* const Kb = (const char*)&KV[buf][0][0][0];
            const char* const Vb = (const char*)&KV[buf][1][0][0];

            // S^T[kb] = K @ U^T over D=64 (4 x K16): col=query, row=key
            f32x16 S[2];
            __builtin_amdgcn_s_setprio(1);
            #pragma unroll
            for (int kb = 0; kb < 2; ++kb) {
                f32x16 s;
                #pragma unroll
                for (int r = 0; r < 16; ++r) s[r] = 0.f;
                #pragma unroll
                for (int dk = 0; dk < 4; ++dk) {
                    const int row = kb * 32 + l31;
                    const bf16x8 kf = *reinterpret_cast<const bf16x8*>(
                        Kb + row * 128 + (((2 * dk + hi) ^ (row & 7)) << 4));
                    s = __builtin_amdgcn_mfma_f32_32x32x16_bf16(kf, qf[dk], s, 0, 0, 0);
                }
                S[kb] = s;
            }
            __builtin_amdgcn_s_setprio(0);

            // mask (diag only) + row max: lane covers 32 of 64 keys
            const bool diag = (kt == myntiles - 1);
            float mx0 = -1e30f, mx1 = -1e30f, mx2 = -1e30f, mx3 = -1e30f;
            if (diag) {
                const int q = q0w + l31;
                #pragma unroll
                for (int kb = 0; kb < 2; ++kb)
                    #pragma unroll
                    for (int r = 0; r < 16; r += 4) {
                        #pragma unroll
                        for (int j = 0; j < 4; ++j) {
                            const int key = k0 + kb * 32 + ((r + j) & 3)
                                          + 8 * ((r + j) >> 2) + 4 * hi;
                            if (key > q) S[kb][r + j] = -1e30f;
                        }
                        mx0 = fmaxf(mx0, S[kb][r + 0]);
                        mx1 = fmaxf(mx1, S[kb][r + 1]);
                        mx2 = fmaxf(mx2, S[kb][r + 2]);
                        mx3 = fmaxf(mx3, S[kb][r + 3]);
                    }
            } else {
                #pragma unroll
                for (int kb = 0; kb < 2; ++kb)
                    #pragma unroll
                    for (int r = 0; r < 16; r += 4) {
                        mx0 = fmaxf(mx0, S[kb][r + 0]);
                        mx1 = fmaxf(mx1, S[kb][r + 1]);
                        mx2 = fmaxf(mx2, S[kb][r + 2]);
                        mx3 = fmaxf(mx3, S[kb][r + 3]);
                    }
            }
            float mx = fmaxf(fmaxf(mx0, mx1), fmaxf(mx2, mx3));
            mx = fmaxf(mx, __shfl_xor(mx, 32));   // combine hi pair: full row max

            // defer-max rescale
            if (!__all(mx - m_ <= RTHR)) {
                const float mnew = fmaxf(m_, mx);
                const float sc = exp2f((m_ - mnew) * KSCALE);
                m_ = mnew;
                l_ *= sc;
                #pragma unroll
                for (int dt = 0; dt < 2; ++dt)
                    #pragma unroll
                    for (int r = 0; r < 16; ++r) O[dt][r] *= sc;
            }

            // exp (clamped: no inf possible) + pack to bf16 dwords
            // w[kb][g][j] = pk(S regs 4g+2j, 4g+2j+1)
            unsigned w[2][4][2];
            float psum = 0.f;
            #pragma unroll
            for (int kb = 0; kb < 2; ++kb)
                #pragma unroll
                for (int g = 0; g < 4; ++g)
                    #pragma unroll
                    for (int j = 0; j < 2; ++j) {
                        const float p0 = exp2f(fminf(
                            (S[kb][4 * g + 2 * j + 0] - m_) * KSCALE, 20.f));
                        const float p1 = exp2f(fminf(
                            (S[kb][4 * g + 2 * j + 1] - m_) * KSCALE, 20.f));
                        psum += p0 + p1;
                        bf16x2 t; t[0] = (bf16_t)p0; t[1] = (bf16_t)p1;
                        w[kb][g][j] = __builtin_bit_cast(unsigned, t);
                    }
            l_ += psum;   // lane-partial; combined in epilogue

            // P B-frags are LANE-LOCAL: frag[kb][ks] = S regs [8ks..8ks+8)
            bf16x8 pfr[2][2];
            #pragma unroll
            for (int kb = 0; kb < 2; ++kb)
                #pragma unroll
                for (int ks = 0; ks < 2; ++ks) {
                    u32x4 fw = {w[kb][2 * ks][0], w[kb][2 * ks][1],
                                w[kb][2 * ks + 1][0], w[kb][2 * ks + 1][1]};
                    pfr[kb][ks] = __builtin_bit_cast(bf16x8, fw);
                }

            // O^T += V^T @ P : A=V^T (kappa-staged), B=P (lane-local)
            __builtin_amdgcn_s_setprio(1);
            #pragma unroll
            for (int dt = 0; dt < 2; ++dt)
                #pragma unroll
                for (int kb = 0; kb < 2; ++kb)
                    #pragma unroll
                    for (int ks = 0; ks < 2; ++ks) {
                        const int row = dt * 32 + l31;
                        const bf16x8 vt = *reinterpret_cast<const bf16x8*>(
                            Vb + row * 128 +
                            (((4 * kb + 2 * ks + hi) ^ (row & 7)) << 4));
                        O[dt] = __builtin_amdgcn_mfma_f32_32x32x16_bf16(
                            vt, pfr[kb][ks], O[dt], 0, 0, 0);
                    }
            __builtin_amdgcn_s_setprio(0);
        }

        asm volatile("s_waitcnt vmcnt(0)" ::: "memory");
        __syncthreads();
        buf ^= 1;
    }

    // epilogue: lane = query q0w+l31; O reg r -> d = dt*32+(r&3)+8*(r>>2)+4*hi
    const float lrow = l_ + __shfl_xor(l_, 32);
    const float inv = 1.f / lrow;
    const size_t grow = rbase + q0w + l31;
    #pragma unroll
    for (int dt = 0; dt < 2; ++dt)
        #pragma unroll
        for (int g2 = 0; g2 < 4; ++g2) {
            bf16x4v o4;
            #pragma unroll
            for (int j = 0; j < 4; ++j) o4[j] = (bf16_t)(O[dt][4 * g2 + j] * inv);
            const int d0 = dt * 32 + 8 * g2 + 4 * hi;
            *reinterpret_cast<bf16x4v*>(&ybf[grow * CC + hcol + d0]) = o4;
        }
}

// ---------------------------------------------------------------------------
extern "C" void kernel_launch(void* const* d_in, const int* in_sizes, int n_in,
                              void* d_out, int out_size, void* d_ws, size_t ws_size,
                              hipStream_t stream)
{
    (void)in_sizes; (void)n_in; (void)out_size; (void)ws_size;
    const float* x  = (const float*)d_in[0];
    const float* Wu = (const float*)d_in[1];
    const float* bu = (const float*)d_in[2];
    const float* Wv = (const float*)d_in[3];
    const float* bv = (const float*)d_in[4];
    const float* W1 = (const float*)d_in[5];
    const float* b1 = (const float*)d_in[6];
    const float* W2 = (const float*)d_in[7];
    const float* b2 = (const float*)d_in[8];
    const float* Wp = (const float*)d_in[9];
    const float* bp = (const float*)d_in[10];
    float* out = (float*)d_out;

    const size_t NE = (size_t)ROWS * CC;
    bf16_t* xbf = (bf16_t*)d_ws;                    // 16 MB
    bf16_t* ubf = xbf + NE;                         // 16 MB
    bf16_t* vp  = ubf + NE;                         // 16 MB
    bf16_t* vbT = vp  + NE;                         // 16 MB
    bf16_t* WuT = vbT + NE;                         // 2 MB
    bf16_t* WvT = WuT + (size_t)CC * CC;            // 2 MB
    bf16_t* WpT = WvT + (size_t)CC * CC;            // 2 MB
    bf16_t* W1T = WpT + (size_t)CC * CC;            // 8 KB
    bf16_t* W2T = W1T + (size_t)HS * HS;            // 8 KB
    bf16_t* ybf = vp;                               // alias: vp dead after gate

    conv_x_kernel<<<ROWS * CC / (256 * 8), 256, 0, stream>>>(x, xbf);
    conv_wt_kernel<<<dim3(16, 16), 256, 0, stream>>>(Wu, WuT);
    conv_wt_kernel<<<dim3(16, 16), 256, 0, stream>>>(Wv, WvT);
    conv_wt_kernel<<<dim3(16, 16), 256, 0, stream>>>(Wp, WpT);
    conv_w64_kernel<<<1, 256, 0, stream>>>(W1, W2, W1T, W2T);

    dim3 gemm_grid(CC / 128, ROWS / 128);           // (8, 64)
    mfma_gemm_kernel<1><<<gemm_grid, 256, 0, stream>>>(xbf, WuT, bu, ubf);
    mfma_gemm_kernel<1><<<gemm_grid, 256, 0, stream>>>(xbf, WvT, bv, vp);
    gate_mfma_kernel<<<dim3(ROWS / 64, HH), 256, 0, stream>>>(
        vp, W1T, W2T, b1, b2, vbT);
    attn_mfma8_kernel<<<dim3(TT / 128, HH, BB), 256, 0, stream>>>(
        ubf, xbf, vbT, ybf);
    mfma_gemm_kernel<0><<<gemm_grid, 256, 0, stream>>>(ybf, WpT, bp, out);
}